// Round 1
// baseline (800.591 us; speedup 1.0000x reference)
//
#include <hip/hip_runtime.h>
#include <hip/hip_bf16.h>

// ---- problem constants ----
#define N_NODES 10000
#define NEDGE   160000
#define ETOT    170000   // edges + self loops

// ---------------- zero ----------------
__global__ void zero_kernel(float* p, size_t n) {
    size_t i = (size_t)blockIdx.x * blockDim.x + threadIdx.x;
    size_t st = (size_t)gridDim.x * blockDim.x;
    for (; i < n; i += st) p[i] = 0.f;
}

// ---------------- tiled fp32 GEMM: C[M,Nc] = A[M,K] @ B[K,Nc] ----------------
__global__ __launch_bounds__(256) void gemm_f32(const float* __restrict__ A,
                                                const float* __restrict__ B,
                                                float* __restrict__ C,
                                                int M, int Nc, int K) {
    const int BM = 64, BN = 64, BK = 16;
    __shared__ float As[BK][BM + 1];
    __shared__ float Bs[BK][BN];
    int tid = threadIdx.x;
    int tx = tid & 15, ty = tid >> 4;
    int row0 = blockIdx.y * BM, col0 = blockIdx.x * BN;
    float acc[4][4] = {};
    for (int k0 = 0; k0 < K; k0 += BK) {
        for (int i = tid; i < BM * BK; i += 256) {
            int r = i >> 4, kk = i & 15;
            int gr = row0 + r;
            As[kk][r] = (gr < M) ? A[(size_t)gr * K + k0 + kk] : 0.f;
        }
        for (int i = tid; i < BK * BN; i += 256) {
            int kk = i >> 6, c = i & 63;
            Bs[kk][c] = B[(size_t)(k0 + kk) * Nc + col0 + c];
        }
        __syncthreads();
#pragma unroll
        for (int kk = 0; kk < BK; ++kk) {
            float a[4], b[4];
#pragma unroll
            for (int i = 0; i < 4; ++i) a[i] = As[kk][ty * 4 + i];
#pragma unroll
            for (int j = 0; j < 4; ++j) b[j] = Bs[kk][tx * 4 + j];
#pragma unroll
            for (int i = 0; i < 4; ++i)
#pragma unroll
                for (int j = 0; j < 4; ++j) acc[i][j] += a[i] * b[j];
        }
        __syncthreads();
    }
    for (int i = 0; i < 4; ++i) {
        int gr = row0 + ty * 4 + i;
        if (gr >= M) continue;
#pragma unroll
        for (int j = 0; j < 4; ++j)
            C[(size_t)gr * Nc + col0 + tx * 4 + j] = acc[i][j];
    }
}

// -------- per-(node,head) attention logits: wave per pair --------
__global__ void logits_kernel(const float* __restrict__ h,
                              const float* __restrict__ a_src,
                              const float* __restrict__ a_dst,
                              float* __restrict__ als, float* __restrict__ ald,
                              int n_pairs, int H, int C) {
    int wid = (int)((blockIdx.x * (size_t)blockDim.x + threadIdx.x) >> 6);
    int lane = threadIdx.x & 63;
    if (wid >= n_pairs) return;
    int n = wid / H, hd = wid % H;
    const float* row = h + (size_t)n * H * C + hd * C;
    const float* as = a_src + hd * C;
    const float* ad = a_dst + hd * C;
    float ps = 0.f, pd = 0.f;
    for (int c = lane; c < C; c += 64) {
        float v = row[c];
        ps += v * as[c];
        pd += v * ad[c];
    }
    for (int off = 32; off; off >>= 1) {
        ps += __shfl_down(ps, off);
        pd += __shfl_down(pd, off);
    }
    if (lane == 0) { als[wid] = ps; ald[wid] = pd; }
}

__device__ __forceinline__ unsigned enc_f32(float f) {
    unsigned u = __float_as_uint(f);
    return (u & 0x80000000u) ? ~u : (u | 0x80000000u);
}
__device__ __forceinline__ float dec_f32(unsigned enc) {
    unsigned u = (enc & 0x80000000u) ? (enc & 0x7FFFFFFFu) : ~enc;
    return __uint_as_float(u);
}

// -------- per-edge: leakyrelu logit, store, atomicMax per dst --------
__global__ void edge_logit_max(const int* __restrict__ ei,
                               const float* __restrict__ als,
                               const float* __restrict__ ald,
                               float* __restrict__ e_out,
                               unsigned* __restrict__ mEnc, int H) {
    int i = blockIdx.x * blockDim.x + threadIdx.x;
    if (i >= ETOT) return;
    int s, d;
    if (i < NEDGE) { s = ei[i]; d = ei[NEDGE + i]; } else { s = d = i - NEDGE; }
    for (int hd = 0; hd < H; ++hd) {
        float e = als[s * H + hd] + ald[d * H + hd];
        e = (e >= 0.f) ? e : 0.2f * e;
        e_out[(size_t)i * H + hd] = e;
        atomicMax(&mEnc[d * H + hd], enc_f32(e));
    }
}

// -------- per-edge: exp(e - m[dst]), store, atomicAdd denom --------
__global__ void edge_expsum(const int* __restrict__ ei,
                            const unsigned* __restrict__ mEnc,
                            float* __restrict__ e_out,
                            float* __restrict__ denom, int H) {
    int i = blockIdx.x * blockDim.x + threadIdx.x;
    if (i >= ETOT) return;
    int d;
    if (i < NEDGE) { d = ei[NEDGE + i]; } else { d = i - NEDGE; }
    for (int hd = 0; hd < H; ++hd) {
        float m = dec_f32(mEnc[d * H + hd]);
        float ex = expf(e_out[(size_t)i * H + hd] - m);
        e_out[(size_t)i * H + hd] = ex;
        atomicAdd(&denom[d * H + hd], ex);
    }
}

// -------- per-edge block: out[dst,:] += h[src,:] * alpha --------
__global__ __launch_bounds__(256) void edge_aggregate(const int* __restrict__ ei,
                                                      const float* __restrict__ hsrc,
                                                      const float* __restrict__ ex,
                                                      const float* __restrict__ denom,
                                                      float* __restrict__ out,
                                                      int H, int C) {
    int i = blockIdx.x;
    int s, d;
    if (i < NEDGE) { s = ei[i]; d = ei[NEDGE + i]; } else { s = d = i - NEDGE; }
    __shared__ float alpha_s[2];
    if (threadIdx.x < H)
        alpha_s[threadIdx.x] = ex[(size_t)i * H + threadIdx.x] / denom[d * H + threadIdx.x];
    __syncthreads();
    int D = H * C;
    const float* hrow = hsrc + (size_t)s * D;
    float* orow = out + (size_t)d * D;
    for (int c = threadIdx.x; c < D; c += blockDim.x) {
        atomicAdd(&orow[c], hrow[c] * alpha_s[c / C]);
    }
}

// -------- elementwise bias + relu (in place) --------
__global__ void bias_relu(float* __restrict__ p, const float* __restrict__ b, int D, size_t n) {
    size_t i = (size_t)blockIdx.x * blockDim.x + threadIdx.x;
    size_t st = (size_t)gridDim.x * blockDim.x;
    for (; i < n; i += st) {
        float v = p[i] + b[i % D];
        p[i] = v > 0.f ? v : 0.f;
    }
}

// -------- column-sum pool: g[c] += sum_n x[n,c] --------
__global__ void pool_kernel(const float* __restrict__ x, float* __restrict__ g, int D) {
    int c = threadIdx.x;   // blockDim = D
    float acc = 0.f;
    for (int n = blockIdx.x; n < N_NODES; n += gridDim.x)
        acc += x[(size_t)n * D + c];
    atomicAdd(&g[c], acc);
}

// -------- final: y = (g/N) @ Wl + bl ; out = y/||y|| --------
__global__ __launch_bounds__(384) void final_kernel(const float* __restrict__ g,
                                                    const float* __restrict__ Wl,
                                                    const float* __restrict__ bl,
                                                    float* __restrict__ out) {
    __shared__ float gs[384];
    __shared__ float red[6];
    int t = threadIdx.x;
    gs[t] = g[t] * (1.f / (float)N_NODES);
    __syncthreads();
    float y = bl[t];
    for (int i = 0; i < 384; ++i) y += gs[i] * Wl[i * 384 + t];
    float sq = y * y;
    for (int off = 32; off; off >>= 1) sq += __shfl_down(sq, off);
    if ((t & 63) == 0) red[t >> 6] = sq;
    __syncthreads();
    if (t == 0) {
        float tot = 0.f;
        for (int i = 0; i < 6; ++i) tot += red[i];
        red[0] = fmaxf(sqrtf(tot), 1e-12f);
    }
    __syncthreads();
    out[t] = y / red[0];
}

extern "C" void kernel_launch(void* const* d_in, const int* in_sizes, int n_in,
                              void* d_out, int out_size, void* d_ws, size_t ws_size,
                              hipStream_t stream) {
    const float* x   = (const float*)d_in[0];
    const int*   ei  = (const int*)d_in[1];
    const float* W1  = (const float*)d_in[2];
    const float* as1 = (const float*)d_in[3];
    const float* ad1 = (const float*)d_in[4];
    const float* b1  = (const float*)d_in[5];
    const float* W2  = (const float*)d_in[6];
    const float* as2 = (const float*)d_in[7];
    const float* ad2 = (const float*)d_in[8];
    const float* b2  = (const float*)d_in[9];
    const float* Wl  = (const float*)d_in[10];
    const float* bl  = (const float*)d_in[11];
    float* out = (float*)d_out;
    float* ws  = (float*)d_ws;

    // ---- workspace layout (floats) ----
    // zero-region (one zero_kernel pass):
    float*    agg1  = ws;                              // N*512 = 5,120,000
    float*    agg2  = agg1 + 5120000;                  // N*384 = 3,840,000
    unsigned* mEnc1 = (unsigned*)(agg2 + 3840000);     // N*2   =    20,000
    float*    den1  = (float*)(mEnc1 + 20000);         // N*2   =    20,000
    unsigned* mEnc2 = (unsigned*)(den1 + 20000);       // N     =    10,000
    float*    den2  = (float*)(mEnc2 + 10000);         // N     =    10,000
    float*    g     = den2 + 10000;                    //            384
    const size_t ZTOT = 9020384;
    // non-zeroed region:
    float* h1   = ws + ZTOT;                           // N*512 = 5,120,000 (h2 aliases)
    float* h2   = h1;                                  // N*384 (h1 dead by then)
    float* als1 = h1 + 5120000;                        // 20,000
    float* ald1 = als1 + 20000;                        // 20,000
    float* als2 = ald1 + 20000;                        // 10,000
    float* ald2 = als2 + 10000;                        // 10,000
    float* e1   = ald2 + 10000;                        // ETOT*2 = 340,000
    float* e2   = e1 + 340000;                         // ETOT   = 170,000

    const int EBLK = (ETOT + 255) / 256;

    // 0. zero accumulators
    zero_kernel<<<2048, 256, 0, stream>>>(ws, ZTOT);

    // ---- layer 1: H=2, C=256, D_in=384, D=512 ----
    {
        dim3 grid(512 / 64, (N_NODES + 63) / 64);
        gemm_f32<<<grid, 256, 0, stream>>>(x, W1, h1, N_NODES, 512, 384);
    }
    {
        int pairs = N_NODES * 2;
        int waves_per_block = 4;
        int blocks = (pairs + waves_per_block - 1) / waves_per_block;
        logits_kernel<<<blocks, 256, 0, stream>>>(h1, as1, ad1, als1, ald1, pairs, 2, 256);
    }
    edge_logit_max<<<EBLK, 256, 0, stream>>>(ei, als1, ald1, e1, mEnc1, 2);
    edge_expsum<<<EBLK, 256, 0, stream>>>(ei, mEnc1, e1, den1, 2);
    edge_aggregate<<<ETOT, 256, 0, stream>>>(ei, h1, e1, den1, agg1, 2, 256);
    bias_relu<<<2048, 256, 0, stream>>>(agg1, b1, 512, (size_t)N_NODES * 512);

    // ---- layer 2: H=1, C=384, D_in=512, D=384 ----
    {
        dim3 grid(384 / 64, (N_NODES + 63) / 64);
        gemm_f32<<<grid, 256, 0, stream>>>(agg1, W2, h2, N_NODES, 384, 512);
    }
    {
        int pairs = N_NODES;
        int blocks = (pairs + 3) / 4;
        logits_kernel<<<blocks, 256, 0, stream>>>(h2, as2, ad2, als2, ald2, pairs, 1, 384);
    }
    edge_logit_max<<<EBLK, 256, 0, stream>>>(ei, als2, ald2, e2, mEnc2, 1);
    edge_expsum<<<EBLK, 256, 0, stream>>>(ei, mEnc2, e2, den2, 1);
    edge_aggregate<<<ETOT, 256, 0, stream>>>(ei, h2, e2, den2, agg2, 1, 384);
    bias_relu<<<2048, 256, 0, stream>>>(agg2, b2, 384, (size_t)N_NODES * 384);

    // ---- pool + final linear + normalize ----
    pool_kernel<<<256, 384, 0, stream>>>(agg2, g, 384);
    final_kernel<<<1, 384, 0, stream>>>(g, Wl, bl, out);
}

// Round 2
// 378.514 us; speedup vs baseline: 2.1151x; 2.1151x over previous
//
#include <hip/hip_runtime.h>
#include <hip/hip_bf16.h>

// ---- problem constants ----
#define N_NODES 10000
#define NEDGE   160000
#define ETOT    170000   // edges + self loops

// ---------------- zero ----------------
__global__ void zero_kernel(float* p, size_t n) {
    size_t i = (size_t)blockIdx.x * blockDim.x + threadIdx.x;
    size_t st = (size_t)gridDim.x * blockDim.x;
    for (; i < n; i += st) p[i] = 0.f;
}

// ---------------- tiled fp32 GEMM: C[M,Nc] = A[M,K] @ B[K,Nc] ----------------
__global__ __launch_bounds__(256) void gemm_f32(const float* __restrict__ A,
                                                const float* __restrict__ B,
                                                float* __restrict__ C,
                                                int M, int Nc, int K) {
    const int BM = 64, BN = 64, BK = 16;
    __shared__ float As[BK][BM + 1];
    __shared__ float Bs[BK][BN];
    int tid = threadIdx.x;
    int tx = tid & 15, ty = tid >> 4;
    int row0 = blockIdx.y * BM, col0 = blockIdx.x * BN;
    float acc[4][4] = {};
    for (int k0 = 0; k0 < K; k0 += BK) {
        for (int i = tid; i < BM * BK; i += 256) {
            int r = i >> 4, kk = i & 15;
            int gr = row0 + r;
            As[kk][r] = (gr < M) ? A[(size_t)gr * K + k0 + kk] : 0.f;
        }
        for (int i = tid; i < BK * BN; i += 256) {
            int kk = i >> 6, c = i & 63;
            Bs[kk][c] = B[(size_t)(k0 + kk) * Nc + col0 + c];
        }
        __syncthreads();
#pragma unroll
        for (int kk = 0; kk < BK; ++kk) {
            float a[4], b[4];
#pragma unroll
            for (int i = 0; i < 4; ++i) a[i] = As[kk][ty * 4 + i];
#pragma unroll
            for (int j = 0; j < 4; ++j) b[j] = Bs[kk][tx * 4 + j];
#pragma unroll
            for (int i = 0; i < 4; ++i)
#pragma unroll
                for (int j = 0; j < 4; ++j) acc[i][j] += a[i] * b[j];
        }
        __syncthreads();
    }
    for (int i = 0; i < 4; ++i) {
        int gr = row0 + ty * 4 + i;
        if (gr >= M) continue;
#pragma unroll
        for (int j = 0; j < 4; ++j)
            C[(size_t)gr * Nc + col0 + tx * 4 + j] = acc[i][j];
    }
}

// -------- per-(node,head) attention logits: wave per pair --------
__global__ void logits_kernel(const float* __restrict__ h,
                              const float* __restrict__ a_src,
                              const float* __restrict__ a_dst,
                              float* __restrict__ als, float* __restrict__ ald,
                              int n_pairs, int H, int C) {
    int wid = (int)((blockIdx.x * (size_t)blockDim.x + threadIdx.x) >> 6);
    int lane = threadIdx.x & 63;
    if (wid >= n_pairs) return;
    int n = wid / H, hd = wid % H;
    const float* row = h + (size_t)n * H * C + hd * C;
    const float* as = a_src + hd * C;
    const float* ad = a_dst + hd * C;
    float ps = 0.f, pd = 0.f;
    for (int c = lane; c < C; c += 64) {
        float v = row[c];
        ps += v * as[c];
        pd += v * ad[c];
    }
    for (int off = 32; off; off >>= 1) {
        ps += __shfl_down(ps, off);
        pd += __shfl_down(pd, off);
    }
    if (lane == 0) { als[wid] = ps; ald[wid] = pd; }
}

// -------- CSR build: count incoming edges per dst --------
__global__ void count_kernel(const int* __restrict__ ei, int* __restrict__ deg) {
    int i = blockIdx.x * blockDim.x + threadIdx.x;
    if (i >= ETOT) return;
    int d = (i < NEDGE) ? ei[NEDGE + i] : (i - NEDGE);
    atomicAdd(&deg[d], 1);
}

// -------- CSR build: exclusive scan (single block, 1024 threads) --------
__global__ __launch_bounds__(1024) void scan_kernel(const int* __restrict__ deg,
                                                    int* __restrict__ offs) {
    __shared__ int tsum[1024];
    int t = threadIdx.x;
    const int PER = (N_NODES + 1023) / 1024;  // 10
    int base = t * PER;
    int local = 0;
    for (int i = 0; i < PER; ++i) {
        int idx = base + i;
        if (idx < N_NODES) local += deg[idx];
    }
    tsum[t] = local;
    __syncthreads();
    for (int off = 1; off < 1024; off <<= 1) {
        int v = (t >= off) ? tsum[t - off] : 0;
        __syncthreads();
        tsum[t] += v;
        __syncthreads();
    }
    int run = (t == 0) ? 0 : tsum[t - 1];
    for (int i = 0; i < PER; ++i) {
        int idx = base + i;
        if (idx < N_NODES) { offs[idx] = run; run += deg[idx]; }
    }
    if (t == 1023) offs[N_NODES] = run;
}

// -------- CSR build: scatter src indices into dst buckets --------
__global__ void scatter_kernel(const int* __restrict__ ei,
                               const int* __restrict__ offs,
                               int* __restrict__ cur, int* __restrict__ csr) {
    int i = blockIdx.x * blockDim.x + threadIdx.x;
    if (i >= ETOT) return;
    int s, d;
    if (i < NEDGE) { s = ei[i]; d = ei[NEDGE + i]; } else { s = d = i - NEDGE; }
    int pos = offs[d] + atomicAdd(&cur[d], 1);
    csr[pos] = s;
}

// -------- fused per-node: softmax over incoming edges + weighted gather
//          + bias + relu, one coalesced output row write --------
#define CHUNK 256
__global__ __launch_bounds__(256) void node_aggregate(
    const int* __restrict__ csr, const int* __restrict__ offs,
    const float* __restrict__ als, const float* __restrict__ ald,
    const float* __restrict__ h, const float* __restrict__ bias,
    float* __restrict__ out, int H, int C) {
    int d = blockIdx.x;
    int tid = threadIdx.x;
    int beg = offs[d], end = offs[d + 1];
    int deg = end - beg;
    int D = H * C;
    __shared__ int   srcs[CHUNK];
    __shared__ float w[2][CHUNK];
    __shared__ float red[4];
    __shared__ float mS[2][2];  // [hd][0]=max, [hd][1]=sum

    // ---- phase A: per-head max and exp-sum over incoming edges ----
    for (int hd = 0; hd < H; ++hd) {
        float aldd = ald[d * H + hd];
        float lm = -3.4e38f;
        for (int j = tid; j < deg; j += 256) {
            int s = csr[beg + j];
            float e = als[s * H + hd] + aldd;
            e = (e >= 0.f) ? e : 0.2f * e;
            lm = fmaxf(lm, e);
        }
        for (int off = 32; off; off >>= 1) lm = fmaxf(lm, __shfl_down(lm, off));
        if ((tid & 63) == 0) red[tid >> 6] = lm;
        __syncthreads();
        float m = fmaxf(fmaxf(red[0], red[1]), fmaxf(red[2], red[3]));
        float ls = 0.f;
        for (int j = tid; j < deg; j += 256) {
            int s = csr[beg + j];
            float e = als[s * H + hd] + aldd;
            e = (e >= 0.f) ? e : 0.2f * e;
            ls += __expf(e - m);
        }
        for (int off = 32; off; off >>= 1) ls += __shfl_down(ls, off);
        __syncthreads();                    // all reads of red done
        if ((tid & 63) == 0) red[tid >> 6] = ls;
        __syncthreads();
        if (tid == 0) { mS[hd][0] = m; mS[hd][1] = red[0] + red[1] + red[2] + red[3]; }
        __syncthreads();
    }

    // ---- phase B: weighted gather-accumulate ----
    int c0 = tid, c1 = tid + 256;
    int hd0 = c0 / C;
    int hd1 = (c1 < D) ? (c1 / C) : 0;
    float acc0 = 0.f, acc1 = 0.f;
    for (int cs = 0; cs < deg; cs += CHUNK) {
        int cnt = min(CHUNK, deg - cs);
        __syncthreads();  // previous chunk reads done before overwrite
        for (int j = tid; j < cnt; j += 256) {
            int s = csr[beg + cs + j];
            srcs[j] = s;
            for (int hd = 0; hd < H; ++hd) {
                float e = als[s * H + hd] + ald[d * H + hd];
                e = (e >= 0.f) ? e : 0.2f * e;
                w[hd][j] = __expf(e - mS[hd][0]) / mS[hd][1];
            }
        }
        __syncthreads();
        for (int j = 0; j < cnt; ++j) {
            int s = srcs[j];
            const float* hr = h + (size_t)s * D;
            acc0 += hr[c0] * w[hd0][j];
            if (c1 < D) acc1 += hr[c1] * w[hd1][j];
        }
    }
    {
        float v = acc0 + bias[c0];
        out[(size_t)d * D + c0] = v > 0.f ? v : 0.f;
    }
    if (c1 < D) {
        float v = acc1 + bias[c1];
        out[(size_t)d * D + c1] = v > 0.f ? v : 0.f;
    }
}

// -------- column-sum pool: g[c] += sum_n x[n,c] --------
__global__ void pool_kernel(const float* __restrict__ x, float* __restrict__ g, int D) {
    int c = threadIdx.x;   // blockDim = D
    float acc = 0.f;
    for (int n = blockIdx.x; n < N_NODES; n += gridDim.x)
        acc += x[(size_t)n * D + c];
    atomicAdd(&g[c], acc);
}

// -------- final: y = (g/N) @ Wl + bl ; out = y/||y|| --------
__global__ __launch_bounds__(384) void final_kernel(const float* __restrict__ g,
                                                    const float* __restrict__ Wl,
                                                    const float* __restrict__ bl,
                                                    float* __restrict__ out) {
    __shared__ float gs[384];
    __shared__ float red[6];
    int t = threadIdx.x;
    gs[t] = g[t] * (1.f / (float)N_NODES);
    __syncthreads();
    float y = bl[t];
    for (int i = 0; i < 384; ++i) y += gs[i] * Wl[i * 384 + t];
    float sq = y * y;
    for (int off = 32; off; off >>= 1) sq += __shfl_down(sq, off);
    if ((t & 63) == 0) red[t >> 6] = sq;
    __syncthreads();
    if (t == 0) {
        float tot = 0.f;
        for (int i = 0; i < 6; ++i) tot += red[i];
        red[0] = fmaxf(sqrtf(tot), 1e-12f);
    }
    __syncthreads();
    out[t] = y / red[0];
}

extern "C" void kernel_launch(void* const* d_in, const int* in_sizes, int n_in,
                              void* d_out, int out_size, void* d_ws, size_t ws_size,
                              hipStream_t stream) {
    const float* x   = (const float*)d_in[0];
    const int*   ei  = (const int*)d_in[1];
    const float* W1  = (const float*)d_in[2];
    const float* as1 = (const float*)d_in[3];
    const float* ad1 = (const float*)d_in[4];
    const float* b1  = (const float*)d_in[5];
    const float* W2  = (const float*)d_in[6];
    const float* as2 = (const float*)d_in[7];
    const float* ad2 = (const float*)d_in[8];
    const float* b2  = (const float*)d_in[9];
    const float* Wl  = (const float*)d_in[10];
    const float* bl  = (const float*)d_in[11];
    float* out = (float*)d_out;
    float* ws  = (float*)d_ws;

    // ---- workspace layout (floats) ----
    float* h1   = ws;                      // N*512 = 5,120,000  (h2 aliases: N*384)
    float* h2   = h1;
    float* agg1 = h1 + 5120000;            // N*512 = 5,120,000  (agg2 aliases: N*384)
    float* agg2 = agg1;
    float* als1 = agg1 + 5120000;          // 20,000
    float* ald1 = als1 + 20000;            // 20,000
    float* als2 = ald1 + 20000;            // 10,000
    float* ald2 = als2 + 10000;            // 10,000
    // zero region (contiguous): g, deg, cur
    float* g    = ald2 + 10000;            // 384
    int*   deg  = (int*)(g + 384);         // 10,000
    int*   cur  = deg + 10000;             // 10,000
    int*   offs = cur + 10000;             // 10,001
    int*   csr  = offs + 10001;            // 170,000
    const size_t ZTOT = 384 + 10000 + 10000;  // g + deg + cur

    const int EBLK = (ETOT + 255) / 256;

    // ---- CSR build (edge list fixed for both layers) ----
    zero_kernel<<<80, 256, 0, stream>>>(g, ZTOT);
    count_kernel<<<EBLK, 256, 0, stream>>>(ei, deg);
    scan_kernel<<<1, 1024, 0, stream>>>(deg, offs);
    scatter_kernel<<<EBLK, 256, 0, stream>>>(ei, offs, cur, csr);

    // ---- layer 1: H=2, C=256, D_in=384, D=512 ----
    {
        dim3 grid(512 / 64, (N_NODES + 63) / 64);
        gemm_f32<<<grid, 256, 0, stream>>>(x, W1, h1, N_NODES, 512, 384);
    }
    {
        int pairs = N_NODES * 2;
        int blocks = (pairs + 3) / 4;
        logits_kernel<<<blocks, 256, 0, stream>>>(h1, as1, ad1, als1, ald1, pairs, 2, 256);
    }
    node_aggregate<<<N_NODES, 256, 0, stream>>>(csr, offs, als1, ald1, h1, b1, agg1, 2, 256);

    // ---- layer 2: H=1, C=384, D_in=512, D=384 ----
    // NOTE: agg1 aliases agg2's buffer; gemm2 reads agg1 -> h2 (aliases h1, h1 dead)
    {
        dim3 grid(384 / 64, (N_NODES + 63) / 64);
        gemm_f32<<<grid, 256, 0, stream>>>(agg1, W2, h2, N_NODES, 384, 512);
    }
    {
        int pairs = N_NODES;
        int blocks = (pairs + 3) / 4;
        logits_kernel<<<blocks, 256, 0, stream>>>(h2, as2, ad2, als2, ald2, pairs, 1, 384);
    }
    node_aggregate<<<N_NODES, 256, 0, stream>>>(csr, offs, als2, ald2, h2, b2, agg2, 1, 384);

    // ---- pool + final linear + normalize ----
    pool_kernel<<<256, 384, 0, stream>>>(agg2, g, 384);
    final_kernel<<<1, 384, 0, stream>>>(g, Wl, bl, out);
}

// Round 3
// 246.833 us; speedup vs baseline: 3.2435x; 1.5335x over previous
//
#include <hip/hip_runtime.h>
#include <hip/hip_bf16.h>

// ---- problem constants ----
#define N_NODES 10000
#define NEDGE   160000
#define ETOT    170000   // edges + self loops

typedef __attribute__((ext_vector_type(4))) float f32x4;
typedef __attribute__((ext_vector_type(8))) short bf16x8;
typedef __attribute__((ext_vector_type(4))) int   int4v;

// f32 -> bf16 bits, round-to-nearest-even (no NaN special-casing needed here)
__device__ __forceinline__ unsigned short f2bf(float f) {
    unsigned u = __float_as_uint(f);
    unsigned r = (u + 0x7fffu + ((u >> 16) & 1u)) >> 16;
    return (unsigned short)r;
}

// ---------------- zero ----------------
__global__ void zero_kernel(float* p, size_t n) {
    size_t i = (size_t)blockIdx.x * blockDim.x + threadIdx.x;
    size_t st = (size_t)gridDim.x * blockDim.x;
    for (; i < n; i += st) p[i] = 0.f;
}

// ---------------- f32 -> bf16 elementwise (n % 4 == 0) ----------------
__global__ void conv_bf16(const float* __restrict__ in, unsigned short* __restrict__ out, int n) {
    int i = (blockIdx.x * blockDim.x + threadIdx.x) * 4;
    if (i >= n) return;
    float4 v = *(const float4*)(in + i);
    unsigned u01 = ((unsigned)f2bf(v.y) << 16) | f2bf(v.x);
    unsigned u23 = ((unsigned)f2bf(v.w) << 16) | f2bf(v.z);
    uint2 pk = {u01, u23};
    *(uint2*)(out + i) = pk;
}

// ---------------- transpose+convert: out[n][k] = bf16(in[k][n]) ----------------
__global__ __launch_bounds__(256) void transp_bf16(const float* __restrict__ in,
                                                   unsigned short* __restrict__ out,
                                                   int K, int N) {
    __shared__ float tile[32][33];
    int k0 = blockIdx.y * 32, n0 = blockIdx.x * 32;
    int tx = threadIdx.x & 31, ty = threadIdx.x >> 5;  // ty 0..7
    for (int i = ty; i < 32; i += 8) {
        int k = k0 + i, n = n0 + tx;
        tile[i][tx] = (k < K && n < N) ? in[(size_t)k * N + n] : 0.f;
    }
    __syncthreads();
    for (int i = ty; i < 32; i += 8) {
        int n = n0 + i, k = k0 + tx;
        if (n < N && k < K) out[(size_t)n * K + k] = f2bf(tile[tx][i]);
    }
}

// ---------------- bf16 MFMA GEMM: C[M][N] f32 = A[M][K] @ Bt[N][K]^T ----------------
// BM=128, BN=64, BK=64; 256 threads = 4 waves in 2x2; wave tile 64x32.
// LDS layout: 16B slots, slot(r,p) holds 8 k-consecutive bf16 of row r at
// k-group (p ^ (r&7))  -> XOR swizzle makes frag ds_read_b128 bank-uniform.
__global__ __launch_bounds__(256) void gemm_mfma(const unsigned short* __restrict__ A,
                                                 const unsigned short* __restrict__ Bt,
                                                 float* __restrict__ C,
                                                 int M, int N, int K) {
    const int BM = 128, BN = 64, BK = 64;
    __shared__ __align__(16) unsigned short As[BM * BK];  // 16 KB
    __shared__ __align__(16) unsigned short Bs[BN * BK];  // 8 KB
    const int tid = threadIdx.x;
    const int l = tid & 63;
    const int w = tid >> 6;
    const int wr = w >> 1, wc = w & 1;
    const int row0 = blockIdx.y * BM, col0 = blockIdx.x * BN;

    f32x4 acc[4][2];
#pragma unroll
    for (int i = 0; i < 4; ++i)
#pragma unroll
        for (int j = 0; j < 2; ++j) acc[i][j] = (f32x4){0.f, 0.f, 0.f, 0.f};

    const int arow = wr * 64 + (l & 15);
    const int brow = wc * 32 + (l & 15);
    const int gbase = l >> 4;

    for (int kt = 0; kt < K; kt += BK) {
        // ---- stage A: 1024 slots, 4 per thread ----
#pragma unroll
        for (int it = 0; it < 4; ++it) {
            int s = tid + it * 256;
            int r = s >> 3, p = s & 7;
            int srcp = p ^ (r & 7);
            int gr = row0 + r; if (gr > M - 1) gr = M - 1;
            int4v v = *(const int4v*)(A + (size_t)gr * K + kt + srcp * 8);
            *(int4v*)(&As[s * 8]) = v;
        }
        // ---- stage B: 512 slots, 2 per thread ----
#pragma unroll
        for (int it = 0; it < 2; ++it) {
            int s = tid + it * 256;
            int r = s >> 3, p = s & 7;
            int srcp = p ^ (r & 7);
            int4v v = *(const int4v*)(Bt + (size_t)(col0 + r) * K + kt + srcp * 8);
            *(int4v*)(&Bs[s * 8]) = v;
        }
        __syncthreads();
#pragma unroll
        for (int ks = 0; ks < 2; ++ks) {
            int g = gbase + ks * 4;
            bf16x8 a[4], b[2];
#pragma unroll
            for (int mi = 0; mi < 4; ++mi) {
                int r = arow + mi * 16;
                a[mi] = *(const bf16x8*)(&As[(r * 8 + (g ^ (r & 7))) * 8]);
            }
#pragma unroll
            for (int ni = 0; ni < 2; ++ni) {
                int r = brow + ni * 16;
                b[ni] = *(const bf16x8*)(&Bs[(r * 8 + (g ^ (r & 7))) * 8]);
            }
#pragma unroll
            for (int mi = 0; mi < 4; ++mi)
#pragma unroll
                for (int ni = 0; ni < 2; ++ni)
                    acc[mi][ni] = __builtin_amdgcn_mfma_f32_16x16x32_bf16(
                        a[mi], b[ni], acc[mi][ni], 0, 0, 0);
        }
        __syncthreads();
    }
    // ---- C write: col = lane&15, row = (lane>>4)*4 + reg ----
#pragma unroll
    for (int mi = 0; mi < 4; ++mi) {
#pragma unroll
        for (int r = 0; r < 4; ++r) {
            int row = row0 + wr * 64 + mi * 16 + (l >> 4) * 4 + r;
            if (row >= M) continue;
#pragma unroll
            for (int ni = 0; ni < 2; ++ni) {
                int col = col0 + wc * 32 + ni * 16 + (l & 15);
                C[(size_t)row * N + col] = acc[mi][ni][r];
            }
        }
    }
}

// -------- per-(node,head) attention logits: wave per pair --------
__global__ void logits_kernel(const float* __restrict__ h,
                              const float* __restrict__ a_src,
                              const float* __restrict__ a_dst,
                              float* __restrict__ als, float* __restrict__ ald,
                              int n_pairs, int H, int C) {
    int wid = (int)((blockIdx.x * (size_t)blockDim.x + threadIdx.x) >> 6);
    int lane = threadIdx.x & 63;
    if (wid >= n_pairs) return;
    int n = wid / H, hd = wid % H;
    const float* row = h + (size_t)n * H * C + hd * C;
    const float* as = a_src + hd * C;
    const float* ad = a_dst + hd * C;
    float ps = 0.f, pd = 0.f;
    for (int c = lane; c < C; c += 64) {
        float v = row[c];
        ps += v * as[c];
        pd += v * ad[c];
    }
    for (int off = 32; off; off >>= 1) {
        ps += __shfl_down(ps, off);
        pd += __shfl_down(pd, off);
    }
    if (lane == 0) { als[wid] = ps; ald[wid] = pd; }
}

// -------- CSR build --------
__global__ void count_kernel(const int* __restrict__ ei, int* __restrict__ deg) {
    int i = blockIdx.x * blockDim.x + threadIdx.x;
    if (i >= ETOT) return;
    int d = (i < NEDGE) ? ei[NEDGE + i] : (i - NEDGE);
    atomicAdd(&deg[d], 1);
}

__global__ __launch_bounds__(1024) void scan_kernel(const int* __restrict__ deg,
                                                    int* __restrict__ offs) {
    __shared__ int tsum[1024];
    int t = threadIdx.x;
    const int PER = (N_NODES + 1023) / 1024;  // 10
    int base = t * PER;
    int local = 0;
    for (int i = 0; i < PER; ++i) {
        int idx = base + i;
        if (idx < N_NODES) local += deg[idx];
    }
    tsum[t] = local;
    __syncthreads();
    for (int off = 1; off < 1024; off <<= 1) {
        int v = (t >= off) ? tsum[t - off] : 0;
        __syncthreads();
        tsum[t] += v;
        __syncthreads();
    }
    int run = (t == 0) ? 0 : tsum[t - 1];
    for (int i = 0; i < PER; ++i) {
        int idx = base + i;
        if (idx < N_NODES) { offs[idx] = run; run += deg[idx]; }
    }
    if (t == 1023) offs[N_NODES] = run;
}

__global__ void scatter_kernel(const int* __restrict__ ei,
                               const int* __restrict__ offs,
                               int* __restrict__ cur, int* __restrict__ csr) {
    int i = blockIdx.x * blockDim.x + threadIdx.x;
    if (i >= ETOT) return;
    int s, d;
    if (i < NEDGE) { s = ei[i]; d = ei[NEDGE + i]; } else { s = d = i - NEDGE; }
    int pos = offs[d] + atomicAdd(&cur[d], 1);
    csr[pos] = s;
}

// -------- fused per-node softmax + weighted gather + bias + relu --------
// exactly one of outF / outB is non-null.
#define CHUNK 256
__global__ __launch_bounds__(256) void node_aggregate(
    const int* __restrict__ csr, const int* __restrict__ offs,
    const float* __restrict__ als, const float* __restrict__ ald,
    const float* __restrict__ h, const float* __restrict__ bias,
    float* __restrict__ outF, unsigned short* __restrict__ outB, int H, int C) {
    int d = blockIdx.x;
    int tid = threadIdx.x;
    int beg = offs[d], end = offs[d + 1];
    int deg = end - beg;
    int D = H * C;
    __shared__ int   srcs[CHUNK];
    __shared__ float w[2][CHUNK];
    __shared__ float red[4];
    __shared__ float mS[2][2];  // [hd][0]=max, [hd][1]=sum

    for (int hd = 0; hd < H; ++hd) {
        float aldd = ald[d * H + hd];
        float lm = -3.4e38f;
        for (int j = tid; j < deg; j += 256) {
            int s = csr[beg + j];
            float e = als[s * H + hd] + aldd;
            e = (e >= 0.f) ? e : 0.2f * e;
            lm = fmaxf(lm, e);
        }
        for (int off = 32; off; off >>= 1) lm = fmaxf(lm, __shfl_down(lm, off));
        if ((tid & 63) == 0) red[tid >> 6] = lm;
        __syncthreads();
        float m = fmaxf(fmaxf(red[0], red[1]), fmaxf(red[2], red[3]));
        float ls = 0.f;
        for (int j = tid; j < deg; j += 256) {
            int s = csr[beg + j];
            float e = als[s * H + hd] + aldd;
            e = (e >= 0.f) ? e : 0.2f * e;
            ls += __expf(e - m);
        }
        for (int off = 32; off; off >>= 1) ls += __shfl_down(ls, off);
        __syncthreads();
        if ((tid & 63) == 0) red[tid >> 6] = ls;
        __syncthreads();
        if (tid == 0) { mS[hd][0] = m; mS[hd][1] = red[0] + red[1] + red[2] + red[3]; }
        __syncthreads();
    }

    int c0 = tid, c1 = tid + 256;
    int hd0 = c0 / C;
    int hd1 = (c1 < D) ? (c1 / C) : 0;
    float acc0 = 0.f, acc1 = 0.f;
    for (int cs = 0; cs < deg; cs += CHUNK) {
        int cnt = min(CHUNK, deg - cs);
        __syncthreads();
        for (int j = tid; j < cnt; j += 256) {
            int s = csr[beg + cs + j];
            srcs[j] = s;
            for (int hd = 0; hd < H; ++hd) {
                float e = als[s * H + hd] + ald[d * H + hd];
                e = (e >= 0.f) ? e : 0.2f * e;
                w[hd][j] = __expf(e - mS[hd][0]) / mS[hd][1];
            }
        }
        __syncthreads();
        for (int j = 0; j < cnt; ++j) {
            int s = srcs[j];
            const float* hr = h + (size_t)s * D;
            acc0 += hr[c0] * w[hd0][j];
            if (c1 < D) acc1 += hr[c1] * w[hd1][j];
        }
    }
    {
        float v = acc0 + bias[c0];
        v = v > 0.f ? v : 0.f;
        if (outF) outF[(size_t)d * D + c0] = v;
        else      outB[(size_t)d * D + c0] = f2bf(v);
    }
    if (c1 < D) {
        float v = acc1 + bias[c1];
        v = v > 0.f ? v : 0.f;
        if (outF) outF[(size_t)d * D + c1] = v;
        else      outB[(size_t)d * D + c1] = f2bf(v);
    }
}

// -------- column-sum pool --------
__global__ void pool_kernel(const float* __restrict__ x, float* __restrict__ g, int D) {
    int c = threadIdx.x;   // blockDim = D
    float acc = 0.f;
    for (int n = blockIdx.x; n < N_NODES; n += gridDim.x)
        acc += x[(size_t)n * D + c];
    atomicAdd(&g[c], acc);
}

// -------- final: y = (g/N) @ Wl + bl ; out = y/||y|| --------
__global__ __launch_bounds__(384) void final_kernel(const float* __restrict__ g,
                                                    const float* __restrict__ Wl,
                                                    const float* __restrict__ bl,
                                                    float* __restrict__ out) {
    __shared__ float gs[384];
    __shared__ float red[6];
    int t = threadIdx.x;
    gs[t] = g[t] * (1.f / (float)N_NODES);
    __syncthreads();
    float y = bl[t];
    for (int i = 0; i < 384; ++i) y += gs[i] * Wl[i * 384 + t];
    float sq = y * y;
    for (int off = 32; off; off >>= 1) sq += __shfl_down(sq, off);
    if ((t & 63) == 0) red[t >> 6] = sq;
    __syncthreads();
    if (t == 0) {
        float tot = 0.f;
        for (int i = 0; i < 6; ++i) tot += red[i];
        red[0] = fmaxf(sqrtf(tot), 1e-12f);
    }
    __syncthreads();
    out[t] = y / red[0];
}

extern "C" void kernel_launch(void* const* d_in, const int* in_sizes, int n_in,
                              void* d_out, int out_size, void* d_ws, size_t ws_size,
                              hipStream_t stream) {
    const float* x   = (const float*)d_in[0];
    const int*   ei  = (const int*)d_in[1];
    const float* W1  = (const float*)d_in[2];
    const float* as1 = (const float*)d_in[3];
    const float* ad1 = (const float*)d_in[4];
    const float* b1  = (const float*)d_in[5];
    const float* W2  = (const float*)d_in[6];
    const float* as2 = (const float*)d_in[7];
    const float* ad2 = (const float*)d_in[8];
    const float* b2  = (const float*)d_in[9];
    const float* Wl  = (const float*)d_in[10];
    const float* bl  = (const float*)d_in[11];
    float* out = (float*)d_out;
    float* ws  = (float*)d_ws;

    // ---- workspace layout (float offsets) ----
    float*          h1    = ws;                                  // 5,120,000 f (h2 aliases)
    float*          h2    = h1;
    unsigned short* xb    = (unsigned short*)(ws + 5120000);     // 3,840,000 sh (1.92M f)
    unsigned short* agg1b = xb + 3840000;                        // 5,120,000 sh (2.56M f)
    float*          agg2  = (float*)xb;                          // 3,840,000 f (xb+agg1b dead by then)
    unsigned short* w1t   = (unsigned short*)(ws + 9600000);     // 196,608 sh
    unsigned short* w2t   = w1t + 196608;                        // 196,608 sh
    float* als1 = ws + 9796608;            // 20,000
    float* ald1 = als1 + 20000;            // 20,000
    float* als2 = ald1 + 20000;            // 10,000
    float* ald2 = als2 + 10000;            // 10,000
    float* g    = ald2 + 10000;            // 384
    int*   deg  = (int*)(g + 384);         // 10,000
    int*   cur  = deg + 10000;             // 10,000
    int*   offs = cur + 10000;             // 10,001
    int*   csr  = offs + 10001;            // 170,000
    const size_t ZTOT = 384 + 10000 + 10000;  // g + deg + cur (contiguous)

    const int EBLK = (ETOT + 255) / 256;

    // ---- CSR build + conversions ----
    zero_kernel<<<80, 256, 0, stream>>>(g, ZTOT);
    count_kernel<<<EBLK, 256, 0, stream>>>(ei, deg);
    scan_kernel<<<1, 1024, 0, stream>>>(deg, offs);
    scatter_kernel<<<EBLK, 256, 0, stream>>>(ei, offs, cur, csr);
    conv_bf16<<<3750, 256, 0, stream>>>(x, xb, N_NODES * 384);
    transp_bf16<<<dim3(16, 12), 256, 0, stream>>>(W1, w1t, 384, 512);
    transp_bf16<<<dim3(12, 16), 256, 0, stream>>>(W2, w2t, 512, 384);

    // ---- layer 1: H=2, C=256, D_in=384, D=512 ----
    gemm_mfma<<<dim3(512 / 64, (N_NODES + 127) / 128), 256, 0, stream>>>(
        xb, w1t, h1, N_NODES, 512, 384);
    logits_kernel<<<(N_NODES * 2 + 3) / 4, 256, 0, stream>>>(h1, as1, ad1, als1, ald1,
                                                             N_NODES * 2, 2, 256);
    node_aggregate<<<N_NODES, 256, 0, stream>>>(csr, offs, als1, ald1, h1, b1,
                                                nullptr, agg1b, 2, 256);

    // ---- layer 2: H=1, C=384, D_in=512, D=384 ----
    gemm_mfma<<<dim3(384 / 64, (N_NODES + 127) / 128), 256, 0, stream>>>(
        agg1b, w2t, h2, N_NODES, 384, 512);
    logits_kernel<<<(N_NODES + 3) / 4, 256, 0, stream>>>(h2, as2, ad2, als2, ald2,
                                                         N_NODES, 1, 384);
    node_aggregate<<<N_NODES, 256, 0, stream>>>(csr, offs, als2, ald2, h2, b2,
                                                agg2, nullptr, 1, 384);

    // ---- pool + final linear + normalize ----
    pool_kernel<<<256, 384, 0, stream>>>(agg2, g, 384);
    final_kernel<<<1, 384, 0, stream>>>(g, Wl, bl, out);
}

// Round 4
// 197.137 us; speedup vs baseline: 4.0611x; 1.2521x over previous
//
#include <hip/hip_runtime.h>
#include <hip/hip_bf16.h>

// ---- problem constants ----
#define N_NODES 10000
#define NEDGE   160000
#define ETOT    170000   // edges + self loops

typedef __attribute__((ext_vector_type(4))) float f32x4;
typedef __attribute__((ext_vector_type(8))) short bf16x8;
typedef __attribute__((ext_vector_type(4))) int   int4v;

// f32 -> bf16 bits, round-to-nearest-even
__device__ __forceinline__ unsigned short f2bf(float f) {
    unsigned u = __float_as_uint(f);
    unsigned r = (u + 0x7fffu + ((u >> 16) & 1u)) >> 16;
    return (unsigned short)r;
}
__device__ __forceinline__ float bf2f_lo(unsigned u) {
    return __uint_as_float((u & 0xffffu) << 16);
}
__device__ __forceinline__ float bf2f_hi(unsigned u) {
    return __uint_as_float(u & 0xffff0000u);
}

// ---------------- zero ----------------
__global__ void zero_kernel(float* p, size_t n) {
    size_t i = (size_t)blockIdx.x * blockDim.x + threadIdx.x;
    size_t st = (size_t)gridDim.x * blockDim.x;
    for (; i < n; i += st) p[i] = 0.f;
}

// ---------------- f32 -> bf16 elementwise (n % 4 == 0) ----------------
__global__ void conv_bf16(const float* __restrict__ in, unsigned short* __restrict__ out, int n) {
    int i = (blockIdx.x * blockDim.x + threadIdx.x) * 4;
    if (i >= n) return;
    float4 v = *(const float4*)(in + i);
    unsigned u01 = ((unsigned)f2bf(v.y) << 16) | f2bf(v.x);
    unsigned u23 = ((unsigned)f2bf(v.w) << 16) | f2bf(v.z);
    uint2 pk = {u01, u23};
    *(uint2*)(out + i) = pk;
}

// ---------------- transpose+convert: out[n][k] = bf16(in[k][n]) ----------------
__global__ __launch_bounds__(256) void transp_bf16(const float* __restrict__ in,
                                                   unsigned short* __restrict__ out,
                                                   int K, int N) {
    __shared__ float tile[32][33];
    int k0 = blockIdx.y * 32, n0 = blockIdx.x * 32;
    int tx = threadIdx.x & 31, ty = threadIdx.x >> 5;  // ty 0..7
    for (int i = ty; i < 32; i += 8) {
        int k = k0 + i, n = n0 + tx;
        tile[i][tx] = (k < K && n < N) ? in[(size_t)k * N + n] : 0.f;
    }
    __syncthreads();
    for (int i = ty; i < 32; i += 8) {
        int n = n0 + i, k = k0 + tx;
        if (n < N && k < K) out[(size_t)n * K + k] = f2bf(tile[tx][i]);
    }
}

// ---------------- bf16 MFMA GEMM: Cb[M][N] bf16 = A[M][K] @ Bt[N][K]^T ----------------
// BM=128, BN=64, BK=64; 256 threads = 4 waves in 2x2; wave tile 64x32.
// LDS: 16B slots, slot(r,p) holds 8 k-consecutive bf16 of row r at k-group
// (p ^ (r&7)) -> XOR swizzle keeps frag ds_read_b128 bank-uniform.
__global__ __launch_bounds__(256) void gemm_mfma(const unsigned short* __restrict__ A,
                                                 const unsigned short* __restrict__ Bt,
                                                 unsigned short* __restrict__ Cb,
                                                 int M, int N, int K) {
    const int BM = 128, BN = 64, BK = 64;
    __shared__ __align__(16) unsigned short As[BM * BK];  // 16 KB
    __shared__ __align__(16) unsigned short Bs[BN * BK];  // 8 KB
    const int tid = threadIdx.x;
    const int l = tid & 63;
    const int w = tid >> 6;
    const int wr = w >> 1, wc = w & 1;
    const int row0 = blockIdx.y * BM, col0 = blockIdx.x * BN;

    f32x4 acc[4][2];
#pragma unroll
    for (int i = 0; i < 4; ++i)
#pragma unroll
        for (int j = 0; j < 2; ++j) acc[i][j] = (f32x4){0.f, 0.f, 0.f, 0.f};

    const int arow = wr * 64 + (l & 15);
    const int brow = wc * 32 + (l & 15);
    const int gbase = l >> 4;

    for (int kt = 0; kt < K; kt += BK) {
#pragma unroll
        for (int it = 0; it < 4; ++it) {
            int s = tid + it * 256;
            int r = s >> 3, p = s & 7;
            int srcp = p ^ (r & 7);
            int gr = row0 + r; if (gr > M - 1) gr = M - 1;
            int4v v = *(const int4v*)(A + (size_t)gr * K + kt + srcp * 8);
            *(int4v*)(&As[s * 8]) = v;
        }
#pragma unroll
        for (int it = 0; it < 2; ++it) {
            int s = tid + it * 256;
            int r = s >> 3, p = s & 7;
            int srcp = p ^ (r & 7);
            int4v v = *(const int4v*)(Bt + (size_t)(col0 + r) * K + kt + srcp * 8);
            *(int4v*)(&Bs[s * 8]) = v;
        }
        __syncthreads();
#pragma unroll
        for (int ks = 0; ks < 2; ++ks) {
            int g = gbase + ks * 4;
            bf16x8 a[4], b[2];
#pragma unroll
            for (int mi = 0; mi < 4; ++mi) {
                int r = arow + mi * 16;
                a[mi] = *(const bf16x8*)(&As[(r * 8 + (g ^ (r & 7))) * 8]);
            }
#pragma unroll
            for (int ni = 0; ni < 2; ++ni) {
                int r = brow + ni * 16;
                b[ni] = *(const bf16x8*)(&Bs[(r * 8 + (g ^ (r & 7))) * 8]);
            }
#pragma unroll
            for (int mi = 0; mi < 4; ++mi)
#pragma unroll
                for (int ni = 0; ni < 2; ++ni)
                    acc[mi][ni] = __builtin_amdgcn_mfma_f32_16x16x32_bf16(
                        a[mi], b[ni], acc[mi][ni], 0, 0, 0);
        }
        __syncthreads();
    }
    // C write (bf16): col = lane&15, row = (lane>>4)*4 + reg
#pragma unroll
    for (int mi = 0; mi < 4; ++mi) {
#pragma unroll
        for (int r = 0; r < 4; ++r) {
            int row = row0 + wr * 64 + mi * 16 + (l >> 4) * 4 + r;
            if (row >= M) continue;
#pragma unroll
            for (int ni = 0; ni < 2; ++ni) {
                int col = col0 + wc * 32 + ni * 16 + (l & 15);
                Cb[(size_t)row * N + col] = f2bf(acc[mi][ni][r]);
            }
        }
    }
}

// -------- per-(node,head) attention logits from bf16 h: wave per pair --------
__global__ void logits_kernel(const unsigned short* __restrict__ h,
                              const float* __restrict__ a_src,
                              const float* __restrict__ a_dst,
                              float* __restrict__ als, float* __restrict__ ald,
                              int n_pairs, int H, int C) {
    int wid = (int)((blockIdx.x * (size_t)blockDim.x + threadIdx.x) >> 6);
    int lane = threadIdx.x & 63;
    if (wid >= n_pairs) return;
    int n = wid / H, hd = wid % H;
    const unsigned short* row = h + (size_t)n * H * C + hd * C;
    const float* as = a_src + hd * C;
    const float* ad = a_dst + hd * C;
    float ps = 0.f, pd = 0.f;
    for (int c = lane * 2; c < C; c += 128) {
        unsigned u = *(const unsigned*)(row + c);
        float v0 = bf2f_lo(u), v1 = bf2f_hi(u);
        ps += v0 * as[c] + v1 * as[c + 1];
        pd += v0 * ad[c] + v1 * ad[c + 1];
    }
    for (int off = 32; off; off >>= 1) {
        ps += __shfl_down(ps, off);
        pd += __shfl_down(pd, off);
    }
    if (lane == 0) { als[wid] = ps; ald[wid] = pd; }
}

// -------- CSR build --------
__global__ void count_kernel(const int* __restrict__ ei, int* __restrict__ deg) {
    int i = blockIdx.x * blockDim.x + threadIdx.x;
    if (i >= ETOT) return;
    int d = (i < NEDGE) ? ei[NEDGE + i] : (i - NEDGE);
    atomicAdd(&deg[d], 1);
}

__global__ __launch_bounds__(1024) void scan_kernel(const int* __restrict__ deg,
                                                    int* __restrict__ offs) {
    __shared__ int tsum[1024];
    int t = threadIdx.x;
    const int PER = (N_NODES + 1023) / 1024;  // 10
    int base = t * PER;
    int local = 0;
    for (int i = 0; i < PER; ++i) {
        int idx = base + i;
        if (idx < N_NODES) local += deg[idx];
    }
    tsum[t] = local;
    __syncthreads();
    for (int off = 1; off < 1024; off <<= 1) {
        int v = (t >= off) ? tsum[t - off] : 0;
        __syncthreads();
        tsum[t] += v;
        __syncthreads();
    }
    int run = (t == 0) ? 0 : tsum[t - 1];
    for (int i = 0; i < PER; ++i) {
        int idx = base + i;
        if (idx < N_NODES) { offs[idx] = run; run += deg[idx]; }
    }
    if (t == 1023) offs[N_NODES] = run;
}

__global__ void scatter_kernel(const int* __restrict__ ei,
                               const int* __restrict__ offs,
                               int* __restrict__ cur, int* __restrict__ csr) {
    int i = blockIdx.x * blockDim.x + threadIdx.x;
    if (i >= ETOT) return;
    int s, d;
    if (i < NEDGE) { s = ei[i]; d = ei[NEDGE + i]; } else { s = d = i - NEDGE; }
    int pos = offs[d] + atomicAdd(&cur[d], 1);
    csr[pos] = s;
}

// -------- fused per-node softmax + weighted bf16 gather + bias + relu -> bf16 --------
#define CHUNK 256
__global__ __launch_bounds__(256) void node_aggregate(
    const int* __restrict__ csr, const int* __restrict__ offs,
    const float* __restrict__ als, const float* __restrict__ ald,
    const unsigned short* __restrict__ h, const float* __restrict__ bias,
    unsigned short* __restrict__ outB, int H, int C) {
    int d = blockIdx.x;
    int tid = threadIdx.x;
    int beg = offs[d], end = offs[d + 1];
    int deg = end - beg;
    int D = H * C;
    __shared__ int   srcs[CHUNK];
    __shared__ float w[2][CHUNK];
    __shared__ float red[4];
    __shared__ float mS[2][2];  // [hd][0]=max, [hd][1]=sum

    // ---- phase A: per-head max and exp-sum over incoming edges ----
    for (int hd = 0; hd < H; ++hd) {
        float aldd = ald[d * H + hd];
        float lm = -3.4e38f;
        for (int j = tid; j < deg; j += 256) {
            int s = csr[beg + j];
            float e = als[s * H + hd] + aldd;
            e = (e >= 0.f) ? e : 0.2f * e;
            lm = fmaxf(lm, e);
        }
        for (int off = 32; off; off >>= 1) lm = fmaxf(lm, __shfl_down(lm, off));
        if ((tid & 63) == 0) red[tid >> 6] = lm;
        __syncthreads();
        float m = fmaxf(fmaxf(red[0], red[1]), fmaxf(red[2], red[3]));
        float ls = 0.f;
        for (int j = tid; j < deg; j += 256) {
            int s = csr[beg + j];
            float e = als[s * H + hd] + aldd;
            e = (e >= 0.f) ? e : 0.2f * e;
            ls += __expf(e - m);
        }
        for (int off = 32; off; off >>= 1) ls += __shfl_down(ls, off);
        __syncthreads();
        if ((tid & 63) == 0) red[tid >> 6] = ls;
        __syncthreads();
        if (tid == 0) { mS[hd][0] = m; mS[hd][1] = red[0] + red[1] + red[2] + red[3]; }
        __syncthreads();
    }

    // ---- phase B: weighted gather (2 adjacent bf16 cols per thread) ----
    int cp = tid * 2;            // columns cp, cp+1 (same head: C is even)
    bool active = cp < D;
    int hd0 = active ? (cp / C) : 0;
    float acc0 = 0.f, acc1 = 0.f;
    for (int cs = 0; cs < deg; cs += CHUNK) {
        int cnt = min(CHUNK, deg - cs);
        __syncthreads();
        for (int j = tid; j < cnt; j += 256) {
            int s = csr[beg + cs + j];
            srcs[j] = s;
            for (int hd = 0; hd < H; ++hd) {
                float e = als[s * H + hd] + ald[d * H + hd];
                e = (e >= 0.f) ? e : 0.2f * e;
                w[hd][j] = __expf(e - mS[hd][0]) / mS[hd][1];
            }
        }
        __syncthreads();
        if (active) {
            for (int j = 0; j < cnt; ++j) {
                int s = srcs[j];
                unsigned u = *(const unsigned*)(h + (size_t)s * D + cp);
                float ww = w[hd0][j];
                acc0 += bf2f_lo(u) * ww;
                acc1 += bf2f_hi(u) * ww;
            }
        }
    }
    if (active) {
        float v0 = acc0 + bias[cp];     v0 = v0 > 0.f ? v0 : 0.f;
        float v1 = acc1 + bias[cp + 1]; v1 = v1 > 0.f ? v1 : 0.f;
        unsigned pk = ((unsigned)f2bf(v1) << 16) | f2bf(v0);
        *(unsigned*)(outB + (size_t)d * D + cp) = pk;
    }
}

// -------- column-sum pool over bf16 --------
__global__ void pool_kernel(const unsigned short* __restrict__ x, float* __restrict__ g, int D) {
    int c = threadIdx.x;   // blockDim = D
    float acc = 0.f;
    for (int n = blockIdx.x; n < N_NODES; n += gridDim.x)
        acc += __uint_as_float((unsigned)x[(size_t)n * D + c] << 16);
    atomicAdd(&g[c], acc);
}

// -------- final: y = (g/N) @ Wl + bl ; out = y/||y|| --------
__global__ __launch_bounds__(384) void final_kernel(const float* __restrict__ g,
                                                    const float* __restrict__ Wl,
                                                    const float* __restrict__ bl,
                                                    float* __restrict__ out) {
    __shared__ float gs[384];
    __shared__ float red[6];
    int t = threadIdx.x;
    gs[t] = g[t] * (1.f / (float)N_NODES);
    __syncthreads();
    float y = bl[t];
    for (int i = 0; i < 384; ++i) y += gs[i] * Wl[i * 384 + t];
    float sq = y * y;
    for (int off = 32; off; off >>= 1) sq += __shfl_down(sq, off);
    if ((t & 63) == 0) red[t >> 6] = sq;
    __syncthreads();
    if (t == 0) {
        float tot = 0.f;
        for (int i = 0; i < 6; ++i) tot += red[i];
        red[0] = fmaxf(sqrtf(tot), 1e-12f);
    }
    __syncthreads();
    out[t] = y / red[0];
}

extern "C" void kernel_launch(void* const* d_in, const int* in_sizes, int n_in,
                              void* d_out, int out_size, void* d_ws, size_t ws_size,
                              hipStream_t stream) {
    const float* x   = (const float*)d_in[0];
    const int*   ei  = (const int*)d_in[1];
    const float* W1  = (const float*)d_in[2];
    const float* as1 = (const float*)d_in[3];
    const float* ad1 = (const float*)d_in[4];
    const float* b1  = (const float*)d_in[5];
    const float* W2  = (const float*)d_in[6];
    const float* as2 = (const float*)d_in[7];
    const float* ad2 = (const float*)d_in[8];
    const float* b2  = (const float*)d_in[9];
    const float* Wl  = (const float*)d_in[10];
    const float* bl  = (const float*)d_in[11];
    float* out = (float*)d_out;
    float* ws  = (float*)d_ws;

    // ---- workspace layout (float units) ----
    unsigned short* h1b   = (unsigned short*)ws;                 // 5,120,000 sh (h2b aliases: 3,840,000 sh)
    unsigned short* h2b   = h1b;
    unsigned short* agg1b = (unsigned short*)(ws + 2560000);     // 5,120,000 sh (agg2b aliases: 3,840,000 sh)
    unsigned short* agg2b = agg1b;
    unsigned short* xb    = (unsigned short*)(ws + 5120000);     // 3,840,000 sh
    unsigned short* w1t   = (unsigned short*)(ws + 7040000);     // 196,608 sh
    unsigned short* w2t   = (unsigned short*)(ws + 7138304);     // 196,608 sh
    float* als1 = ws + 7236608;            // 20,000
    float* ald1 = als1 + 20000;            // 20,000
    float* als2 = ald1 + 20000;            // 10,000
    float* ald2 = als2 + 10000;            // 10,000
    float* g    = ald2 + 10000;            // 384
    int*   deg  = (int*)(g + 384);         // 10,000
    int*   cur  = deg + 10000;             // 10,000
    int*   offs = cur + 10000;             // 10,001
    int*   csr  = offs + 10001;            // 170,000
    const size_t ZTOT = 384 + 10000 + 10000;  // g + deg + cur (contiguous)

    const int EBLK = (ETOT + 255) / 256;

    // ---- CSR build + conversions ----
    zero_kernel<<<80, 256, 0, stream>>>(g, ZTOT);
    count_kernel<<<EBLK, 256, 0, stream>>>(ei, deg);
    scan_kernel<<<1, 1024, 0, stream>>>(deg, offs);
    scatter_kernel<<<EBLK, 256, 0, stream>>>(ei, offs, cur, csr);
    conv_bf16<<<3750, 256, 0, stream>>>(x, xb, N_NODES * 384);
    transp_bf16<<<dim3(16, 12), 256, 0, stream>>>(W1, w1t, 384, 512);
    transp_bf16<<<dim3(12, 16), 256, 0, stream>>>(W2, w2t, 512, 384);

    // ---- layer 1: H=2, C=256, D_in=384, D=512 ----
    gemm_mfma<<<dim3(512 / 64, (N_NODES + 127) / 128), 256, 0, stream>>>(
        xb, w1t, h1b, N_NODES, 512, 384);
    logits_kernel<<<(N_NODES * 2 + 3) / 4, 256, 0, stream>>>(h1b, as1, ad1, als1, ald1,
                                                             N_NODES * 2, 2, 256);
    node_aggregate<<<N_NODES, 256, 0, stream>>>(csr, offs, als1, ald1, h1b, b1,
                                                agg1b, 2, 256);

    // ---- layer 2: H=1, C=384, D_in=512, D=384 ----
    gemm_mfma<<<dim3(384 / 64, (N_NODES + 127) / 128), 256, 0, stream>>>(
        agg1b, w2t, h2b, N_NODES, 384, 512);
    logits_kernel<<<(N_NODES + 3) / 4, 256, 0, stream>>>(h2b, as2, ad2, als2, ald2,
                                                         N_NODES, 1, 384);
    node_aggregate<<<N_NODES, 256, 0, stream>>>(csr, offs, als2, ald2, h2b, b2,
                                                agg2b, 1, 384);

    // ---- pool + final linear + normalize ----
    pool_kernel<<<256, 384, 0, stream>>>(agg2b, g, 384);
    final_kernel<<<1, 384, 0, stream>>>(g, Wl, bl, out);
}

// Round 6
// 172.422 us; speedup vs baseline: 4.6432x; 1.1433x over previous
//
#include <hip/hip_runtime.h>
#include <hip/hip_bf16.h>

// ---- problem constants ----
#define N_NODES 10000
#define NEDGE   160000
#define ETOT    170000   // edges + self loops

typedef __attribute__((ext_vector_type(4))) float f32x4;
typedef __attribute__((ext_vector_type(8))) short bf16x8;
typedef __attribute__((ext_vector_type(4))) int   int4v;

// f32 -> bf16 bits, round-to-nearest-even
__device__ __forceinline__ unsigned short f2bf(float f) {
    unsigned u = __float_as_uint(f);
    unsigned r = (u + 0x7fffu + ((u >> 16) & 1u)) >> 16;
    return (unsigned short)r;
}
__device__ __forceinline__ float bf2f_lo(unsigned u) {
    return __uint_as_float((u & 0xffffu) << 16);
}
__device__ __forceinline__ float bf2f_hi(unsigned u) {
    return __uint_as_float(u & 0xffff0000u);
}

__device__ __forceinline__ float wred_max(float v) {
#pragma unroll
    for (int o = 32; o; o >>= 1) v = fmaxf(v, __shfl_xor(v, o));
    return v;
}
__device__ __forceinline__ float wred_sum(float v) {
#pragma unroll
    for (int o = 32; o; o >>= 1) v += __shfl_xor(v, o);
    return v;
}

// ---------------- zero ----------------
__global__ void zero_kernel(float* p, size_t n) {
    size_t i = (size_t)blockIdx.x * blockDim.x + threadIdx.x;
    size_t st = (size_t)gridDim.x * blockDim.x;
    for (; i < n; i += st) p[i] = 0.f;
}

// ---------------- f32 -> bf16 elementwise (n % 4 == 0) ----------------
__global__ void conv_bf16(const float* __restrict__ in, unsigned short* __restrict__ out, int n) {
    int i = (blockIdx.x * blockDim.x + threadIdx.x) * 4;
    if (i >= n) return;
    float4 v = *(const float4*)(in + i);
    unsigned u01 = ((unsigned)f2bf(v.y) << 16) | f2bf(v.x);
    unsigned u23 = ((unsigned)f2bf(v.w) << 16) | f2bf(v.z);
    uint2 pk = {u01, u23};
    *(uint2*)(out + i) = pk;
}

// ---------------- transpose+convert: out[n][k] = bf16(in[k][n]) ----------------
__global__ __launch_bounds__(256) void transp_bf16(const float* __restrict__ in,
                                                   unsigned short* __restrict__ out,
                                                   int K, int N) {
    __shared__ float tile[32][33];
    int k0 = blockIdx.y * 32, n0 = blockIdx.x * 32;
    int tx = threadIdx.x & 31, ty = threadIdx.x >> 5;  // ty 0..7
    for (int i = ty; i < 32; i += 8) {
        int k = k0 + i, n = n0 + tx;
        tile[i][tx] = (k < K && n < N) ? in[(size_t)k * N + n] : 0.f;
    }
    __syncthreads();
    for (int i = ty; i < 32; i += 8) {
        int n = n0 + i, k = k0 + tx;
        if (n < N && k < K) out[(size_t)n * K + k] = f2bf(tile[tx][i]);
    }
}

// ---------------- bf16 MFMA GEMM: Cb[M][N] bf16 = A[M][K] @ Bt[N][K]^T ----------------
__global__ __launch_bounds__(256) void gemm_mfma(const unsigned short* __restrict__ A,
                                                 const unsigned short* __restrict__ Bt,
                                                 unsigned short* __restrict__ Cb,
                                                 int M, int N, int K) {
    const int BM = 128, BN = 64, BK = 64;
    __shared__ __align__(16) unsigned short As[BM * BK];  // 16 KB
    __shared__ __align__(16) unsigned short Bs[BN * BK];  // 8 KB
    const int tid = threadIdx.x;
    const int l = tid & 63;
    const int w = tid >> 6;
    const int wr = w >> 1, wc = w & 1;
    const int row0 = blockIdx.y * BM, col0 = blockIdx.x * BN;

    f32x4 acc[4][2];
#pragma unroll
    for (int i = 0; i < 4; ++i)
#pragma unroll
        for (int j = 0; j < 2; ++j) acc[i][j] = (f32x4){0.f, 0.f, 0.f, 0.f};

    const int arow = wr * 64 + (l & 15);
    const int brow = wc * 32 + (l & 15);
    const int gbase = l >> 4;

    for (int kt = 0; kt < K; kt += BK) {
#pragma unroll
        for (int it = 0; it < 4; ++it) {
            int s = tid + it * 256;
            int r = s >> 3, p = s & 7;
            int srcp = p ^ (r & 7);
            int gr = row0 + r; if (gr > M - 1) gr = M - 1;
            int4v v = *(const int4v*)(A + (size_t)gr * K + kt + srcp * 8);
            *(int4v*)(&As[s * 8]) = v;
        }
#pragma unroll
        for (int it = 0; it < 2; ++it) {
            int s = tid + it * 256;
            int r = s >> 3, p = s & 7;
            int srcp = p ^ (r & 7);
            int4v v = *(const int4v*)(Bt + (size_t)(col0 + r) * K + kt + srcp * 8);
            *(int4v*)(&Bs[s * 8]) = v;
        }
        __syncthreads();
#pragma unroll
        for (int ks = 0; ks < 2; ++ks) {
            int g = gbase + ks * 4;
            bf16x8 a[4], b[2];
#pragma unroll
            for (int mi = 0; mi < 4; ++mi) {
                int r = arow + mi * 16;
                a[mi] = *(const bf16x8*)(&As[(r * 8 + (g ^ (r & 7))) * 8]);
            }
#pragma unroll
            for (int ni = 0; ni < 2; ++ni) {
                int r = brow + ni * 16;
                b[ni] = *(const bf16x8*)(&Bs[(r * 8 + (g ^ (r & 7))) * 8]);
            }
#pragma unroll
            for (int mi = 0; mi < 4; ++mi)
#pragma unroll
                for (int ni = 0; ni < 2; ++ni)
                    acc[mi][ni] = __builtin_amdgcn_mfma_f32_16x16x32_bf16(
                        a[mi], b[ni], acc[mi][ni], 0, 0, 0);
        }
        __syncthreads();
    }
#pragma unroll
    for (int mi = 0; mi < 4; ++mi) {
#pragma unroll
        for (int r = 0; r < 4; ++r) {
            int row = row0 + wr * 64 + mi * 16 + (l >> 4) * 4 + r;
            if (row >= M) continue;
#pragma unroll
            for (int ni = 0; ni < 2; ++ni) {
                int col = col0 + wc * 32 + ni * 16 + (l & 15);
                Cb[(size_t)row * N + col] = f2bf(acc[mi][ni][r]);
            }
        }
    }
}

// -------- per-(node,head) attention logits from bf16 h: wave per pair --------
__global__ void logits_kernel(const unsigned short* __restrict__ h,
                              const float* __restrict__ a_src,
                              const float* __restrict__ a_dst,
                              float* __restrict__ als, float* __restrict__ ald,
                              int n_pairs, int H, int C) {
    int wid = (int)((blockIdx.x * (size_t)blockDim.x + threadIdx.x) >> 6);
    int lane = threadIdx.x & 63;
    if (wid >= n_pairs) return;
    int n = wid / H, hd = wid % H;
    const unsigned short* row = h + (size_t)n * H * C + hd * C;
    const float* as = a_src + hd * C;
    const float* ad = a_dst + hd * C;
    float ps = 0.f, pd = 0.f;
    for (int c = lane * 2; c < C; c += 128) {
        unsigned u = *(const unsigned*)(row + c);
        float v0 = bf2f_lo(u), v1 = bf2f_hi(u);
        ps += v0 * as[c] + v1 * as[c + 1];
        pd += v0 * ad[c] + v1 * ad[c + 1];
    }
    for (int off = 32; off; off >>= 1) {
        ps += __shfl_down(ps, off);
        pd += __shfl_down(pd, off);
    }
    if (lane == 0) { als[wid] = ps; ald[wid] = pd; }
}

// -------- CSR build --------
__global__ void count_kernel(const int* __restrict__ ei, int* __restrict__ deg) {
    int i = blockIdx.x * blockDim.x + threadIdx.x;
    if (i >= ETOT) return;
    int d = (i < NEDGE) ? ei[NEDGE + i] : (i - NEDGE);
    atomicAdd(&deg[d], 1);
}

__global__ __launch_bounds__(1024) void scan_kernel(const int* __restrict__ deg,
                                                    int* __restrict__ offs) {
    __shared__ int tsum[1024];
    int t = threadIdx.x;
    const int PER = (N_NODES + 1023) / 1024;  // 10
    int base = t * PER;
    int local = 0;
    for (int i = 0; i < PER; ++i) {
        int idx = base + i;
        if (idx < N_NODES) local += deg[idx];
    }
    tsum[t] = local;
    __syncthreads();
    for (int off = 1; off < 1024; off <<= 1) {
        int v = (t >= off) ? tsum[t - off] : 0;
        __syncthreads();
        tsum[t] += v;
        __syncthreads();
    }
    int run = (t == 0) ? 0 : tsum[t - 1];
    for (int i = 0; i < PER; ++i) {
        int idx = base + i;
        if (idx < N_NODES) { offs[idx] = run; run += deg[idx]; }
    }
    if (t == 1023) offs[N_NODES] = run;
}

__global__ void scatter_kernel(const int* __restrict__ ei,
                               const int* __restrict__ offs,
                               int* __restrict__ cur, int* __restrict__ csr) {
    int i = blockIdx.x * blockDim.x + threadIdx.x;
    if (i >= ETOT) return;
    int s, d;
    if (i < NEDGE) { s = ei[i]; d = ei[NEDGE + i]; } else { s = d = i - NEDGE; }
    int pos = offs[d] + atomicAdd(&cur[d], 1);
    csr[pos] = s;
}

// -------- layer-1 aggregate: one wave per dst node, flash-style online softmax.
// H=2, C=256, D=512. Lane covers cols 8l..8l+7; head = l<32?0:1.
// All cross-lane ops CONVERGENT (both heads' shfls executed by all lanes).
__global__ __launch_bounds__(256) void node_agg1(
    const int* __restrict__ csr, const int* __restrict__ offs,
    const float* __restrict__ als, const float* __restrict__ ald,
    const unsigned short* __restrict__ h, const float* __restrict__ bias,
    unsigned short* __restrict__ outB) {
    int d = blockIdx.x * 4 + (threadIdx.x >> 6);
    int lane = threadIdx.x & 63;
    if (d >= N_NODES) return;
    int beg = offs[d], deg = offs[d + 1] - beg;
    float ald0 = ald[d * 2], ald1 = ald[d * 2 + 1];
    float m0 = -3.4e38f, m1 = -3.4e38f, s0 = 0.f, s1 = 0.f;
    float acc[8] = {};
    for (int base = 0; base < deg; base += 64) {
        int j = base + lane;
        int cnt = min(64, deg - base);
        int srcj = 0;
        float e0 = -3.4e38f, e1 = -3.4e38f;
        if (j < deg) {
            srcj = csr[beg + j];
            e0 = als[srcj * 2] + ald0;     e0 = (e0 >= 0.f) ? e0 : 0.2f * e0;
            e1 = als[srcj * 2 + 1] + ald1; e1 = (e1 >= 0.f) ? e1 : 0.2f * e1;
        }
        float nm0 = fmaxf(m0, wred_max(e0));
        float nm1 = fmaxf(m1, wred_max(e1));
        float r0 = __expf(m0 - nm0), r1 = __expf(m1 - nm1);
        float p0 = (j < deg) ? __expf(e0 - nm0) : 0.f;
        float p1 = (j < deg) ? __expf(e1 - nm1) : 0.f;
        s0 = s0 * r0 + wred_sum(p0);
        s1 = s1 * r1 + wred_sum(p1);
        m0 = nm0; m1 = nm1;
        float racc = (lane < 32) ? r0 : r1;
#pragma unroll
        for (int k = 0; k < 8; ++k) acc[k] *= racc;
        for (int jj = 0; jj < cnt; ++jj) {
            int s = __shfl(srcj, jj);
            float w0 = __shfl(p0, jj);     // convergent: all 64 lanes
            float w1 = __shfl(p1, jj);     // convergent: all 64 lanes
            float wgt = (lane < 32) ? w0 : w1;  // plain select, no cross-lane
            int4v u = *(const int4v*)(h + (size_t)s * 512 + lane * 8);
#pragma unroll
            for (int q = 0; q < 4; ++q) {
                unsigned uu = (unsigned)u[q];
                acc[2 * q]     += bf2f_lo(uu) * wgt;
                acc[2 * q + 1] += bf2f_hi(uu) * wgt;
            }
        }
    }
    float inv = 1.f / ((lane < 32) ? s0 : s1);
    int c0 = lane * 8;
    unsigned* orow = (unsigned*)(outB + (size_t)d * 512 + c0);
#pragma unroll
    for (int q = 0; q < 4; ++q) {
        float v0 = acc[2 * q] * inv + bias[c0 + 2 * q];
        float v1 = acc[2 * q + 1] * inv + bias[c0 + 2 * q + 1];
        v0 = v0 > 0.f ? v0 : 0.f;
        v1 = v1 > 0.f ? v1 : 0.f;
        orow[q] = ((unsigned)f2bf(v1) << 16) | f2bf(v0);
    }
}

// -------- layer-2 aggregate: one wave per dst node. H=1, C=D=384.
__global__ __launch_bounds__(256) void node_agg2(
    const int* __restrict__ csr, const int* __restrict__ offs,
    const float* __restrict__ als, const float* __restrict__ ald,
    const unsigned short* __restrict__ h, const float* __restrict__ bias,
    unsigned short* __restrict__ outB) {
    int d = blockIdx.x * 4 + (threadIdx.x >> 6);
    int lane = threadIdx.x & 63;
    if (d >= N_NODES) return;
    int beg = offs[d], deg = offs[d + 1] - beg;
    float ald0 = ald[d];
    float m0 = -3.4e38f, s0 = 0.f;
    float acc[6] = {};
    for (int base = 0; base < deg; base += 64) {
        int j = base + lane;
        int cnt = min(64, deg - base);
        int srcj = 0;
        float e0 = -3.4e38f;
        if (j < deg) {
            srcj = csr[beg + j];
            e0 = als[srcj] + ald0; e0 = (e0 >= 0.f) ? e0 : 0.2f * e0;
        }
        float nm0 = fmaxf(m0, wred_max(e0));
        float r0 = __expf(m0 - nm0);
        float p0 = (j < deg) ? __expf(e0 - nm0) : 0.f;
        s0 = s0 * r0 + wred_sum(p0);
        m0 = nm0;
#pragma unroll
        for (int k = 0; k < 6; ++k) acc[k] *= r0;
        for (int jj = 0; jj < cnt; ++jj) {
            int s = __shfl(srcj, jj);
            float wgt = __shfl(p0, jj);
            const unsigned* hrow = (const unsigned*)(h + (size_t)s * 384);
#pragma unroll
            for (int it = 0; it < 3; ++it) {
                unsigned uu = hrow[lane + it * 64];
                acc[2 * it]     += bf2f_lo(uu) * wgt;
                acc[2 * it + 1] += bf2f_hi(uu) * wgt;
            }
        }
    }
    float inv = 1.f / s0;
    unsigned* orow = (unsigned*)(outB + (size_t)d * 384);
#pragma unroll
    for (int it = 0; it < 3; ++it) {
        int c = (lane + it * 64) * 2;
        float v0 = acc[2 * it] * inv + bias[c];
        float v1 = acc[2 * it + 1] * inv + bias[c + 1];
        v0 = v0 > 0.f ? v0 : 0.f;
        v1 = v1 > 0.f ? v1 : 0.f;
        orow[lane + it * 64] = ((unsigned)f2bf(v1) << 16) | f2bf(v0);
    }
}

// -------- column-sum pool over bf16 --------
__global__ void pool_kernel(const unsigned short* __restrict__ x, float* __restrict__ g, int D) {
    int c = threadIdx.x;   // blockDim = D
    float acc = 0.f;
    for (int n = blockIdx.x; n < N_NODES; n += gridDim.x)
        acc += __uint_as_float((unsigned)x[(size_t)n * D + c] << 16);
    atomicAdd(&g[c], acc);
}

// -------- final: y = (g/N) @ Wl + bl ; out = y/||y|| --------
__global__ __launch_bounds__(384) void final_kernel(const float* __restrict__ g,
                                                    const float* __restrict__ Wl,
                                                    const float* __restrict__ bl,
                                                    float* __restrict__ out) {
    __shared__ float gs[384];
    __shared__ float red[6];
    int t = threadIdx.x;
    gs[t] = g[t] * (1.f / (float)N_NODES);
    __syncthreads();
    float y = bl[t];
    for (int i = 0; i < 384; ++i) y += gs[i] * Wl[i * 384 + t];
    float sq = y * y;
    for (int off = 32; off; off >>= 1) sq += __shfl_down(sq, off);
    if ((t & 63) == 0) red[t >> 6] = sq;
    __syncthreads();
    if (t == 0) {
        float tot = 0.f;
        for (int i = 0; i < 6; ++i) tot += red[i];
        red[0] = fmaxf(sqrtf(tot), 1e-12f);
    }
    __syncthreads();
    out[t] = y / red[0];
}

extern "C" void kernel_launch(void* const* d_in, const int* in_sizes, int n_in,
                              void* d_out, int out_size, void* d_ws, size_t ws_size,
                              hipStream_t stream) {
    const float* x   = (const float*)d_in[0];
    const int*   ei  = (const int*)d_in[1];
    const float* W1  = (const float*)d_in[2];
    const float* as1 = (const float*)d_in[3];
    const float* ad1 = (const float*)d_in[4];
    const float* b1  = (const float*)d_in[5];
    const float* W2  = (const float*)d_in[6];
    const float* as2 = (const float*)d_in[7];
    const float* ad2 = (const float*)d_in[8];
    const float* b2  = (const float*)d_in[9];
    const float* Wl  = (const float*)d_in[10];
    const float* bl  = (const float*)d_in[11];
    float* out = (float*)d_out;
    float* ws  = (float*)d_ws;

    // ---- workspace layout (float units) ----
    unsigned short* h1b   = (unsigned short*)ws;                 // 5,120,000 sh (h2b aliases)
    unsigned short* h2b   = h1b;
    unsigned short* agg1b = (unsigned short*)(ws + 2560000);     // 5,120,000 sh (agg2b aliases)
    unsigned short* agg2b = agg1b;
    unsigned short* xb    = (unsigned short*)(ws + 5120000);     // 3,840,000 sh
    unsigned short* w1t   = (unsigned short*)(ws + 7040000);     // 196,608 sh
    unsigned short* w2t   = (unsigned short*)(ws + 7138304);     // 196,608 sh
    float* als1 = ws + 7236608;            // 20,000
    float* ald1 = als1 + 20000;            // 20,000
    float* als2 = ald1 + 20000;            // 10,000
    float* ald2 = als2 + 10000;            // 10,000
    float* g    = ald2 + 10000;            // 384
    int*   deg  = (int*)(g + 384);         // 10,000
    int*   cur  = deg + 10000;             // 10,000
    int*   offs = cur + 10000;             // 10,001
    int*   csr  = offs + 10001;            // 170,000
    const size_t ZTOT = 384 + 10000 + 10000;  // g + deg + cur (contiguous)

    const int EBLK = (ETOT + 255) / 256;

    // ---- CSR build + conversions ----
    zero_kernel<<<80, 256, 0, stream>>>(g, ZTOT);
    count_kernel<<<EBLK, 256, 0, stream>>>(ei, deg);
    scan_kernel<<<1, 1024, 0, stream>>>(deg, offs);
    scatter_kernel<<<EBLK, 256, 0, stream>>>(ei, offs, cur, csr);
    conv_bf16<<<3750, 256, 0, stream>>>(x, xb, N_NODES * 384);
    transp_bf16<<<dim3(16, 12), 256, 0, stream>>>(W1, w1t, 384, 512);
    transp_bf16<<<dim3(12, 16), 256, 0, stream>>>(W2, w2t, 512, 384);

    // ---- layer 1: H=2, C=256, D_in=384, D=512 ----
    gemm_mfma<<<dim3(512 / 64, (N_NODES + 127) / 128), 256, 0, stream>>>(
        xb, w1t, h1b, N_NODES, 512, 384);
    logits_kernel<<<(N_NODES * 2 + 3) / 4, 256, 0, stream>>>(h1b, as1, ad1, als1, ald1,
                                                             N_NODES * 2, 2, 256);
    node_agg1<<<(N_NODES + 3) / 4, 256, 0, stream>>>(csr, offs, als1, ald1, h1b, b1, agg1b);

    // ---- layer 2: H=1, C=384, D_in=512, D=384 ----
    gemm_mfma<<<dim3(384 / 64, (N_NODES + 127) / 128), 256, 0, stream>>>(
        agg1b, w2t, h2b, N_NODES, 384, 512);
    logits_kernel<<<(N_NODES + 3) / 4, 256, 0, stream>>>(h2b, as2, ad2, als2, ald2,
                                                         N_NODES, 1, 384);
    node_agg2<<<(N_NODES + 3) / 4, 256, 0, stream>>>(csr, offs, als2, ald2, h2b, b2, agg2b);

    // ---- pool + final linear + normalize ----
    pool_kernel<<<256, 384, 0, stream>>>(agg2b, g, 384);
    final_kernel<<<1, 384, 0, stream>>>(g, Wl, bl, out);
}